// Round 20
// baseline (84.440 us; speedup 1.0000x reference)
//
#include <hip/hip_runtime.h>

// DIN attention pooling — round 20: R18 body + len-skip + LPT dynamic queue.
//   Wb[e][h] = (W1b-W1c)[e][h] + q_e*W1d[e][h];  qh[h] = b1[h] + q @ (W1a+W1c)
//   H = sig(K@Wb + qh); G = sig(H@W2 + b2); s = G@W3 + b3 (masked); out = s^T K
// R19 lesson: len-skip (FETCH 52->34MB) + static all-resident grid = idle
// slots (occupancy 24->12.6%) => net regression. R20: persistent waves
// (grid 1792 = 7/CU < 2048 units) pop b's from an atomic queue sorted by
// len DESCENDING (counting-sort prep into d_ws) — hardware LPT balancing.
// Pop order nondeterministic; output per-b is a plain store => deterministic.
// REGISTER LAW (R6/R8/R11 vs R7/R9/R12): keep the 170-reg class (bound ,3).

constexpr int Bn = 2048, Tn = 200, En = 64;
constexpr int HS_W  = 84;                // H slab stride (f16), conflict-free
constexpr int HSLAB = 16 * HS_W + 48;    // 1392: covers row-15 aH2 read to 1388

typedef _Float16 f16;
typedef _Float16 f16x2 __attribute__((ext_vector_type(2)));
typedef _Float16 f16x8 __attribute__((ext_vector_type(8)));
typedef float f32x4 __attribute__((ext_vector_type(4)));

__device__ __align__(16) f16 g_wkf[80 * 64];    // [h][e]  W1b - W1c
__device__ __align__(16) f16 g_wqf[80 * 64];    // [h][e]  W1d
__device__ __align__(16) f16 g_wsumT[80 * 64];  // [h][e]  W1a + W1c
__device__ __align__(16) f16 g_w2t[48 * 96];    // [j][h]  W2^T, zeros j>=40 or h>=80

__device__ __forceinline__ float fsig(float x) {
  return __fdividef(1.0f, 1.0f + __expf(-x));
}

template <int CTRL>
__device__ __forceinline__ float dpp_add(float x) {
  int y = __builtin_amdgcn_update_dpp(0, __builtin_bit_cast(int, x),
                                      CTRL, 0xf, 0xf, true);
  return x + __builtin_bit_cast(float, y);
}
__device__ __forceinline__ float row16_sum(float x) {
  x = dpp_add<0x121>(x);
  x = dpp_add<0x122>(x);
  x = dpp_add<0x124>(x);
  x = dpp_add<0x128>(x);
  return x;
}

__device__ __forceinline__ f16x8 pack8(float4 a, float4 b) {
  union { f16x2 p[4]; f16x8 v; } u;
  u.p[0] = __builtin_bit_cast(f16x2, __builtin_amdgcn_cvt_pkrtz(a.x, a.y));
  u.p[1] = __builtin_bit_cast(f16x2, __builtin_amdgcn_cvt_pkrtz(a.z, a.w));
  u.p[2] = __builtin_bit_cast(f16x2, __builtin_amdgcn_cvt_pkrtz(b.x, b.y));
  u.p[3] = __builtin_bit_cast(f16x2, __builtin_amdgcn_cvt_pkrtz(b.z, b.w));
  return u.v;
}

__global__ __launch_bounds__(256) void din_prep(const float* __restrict__ W1,
                                                const float* __restrict__ W2) {
  int idx = blockIdx.x * 256 + threadIdx.x;   // grid 20 -> 5120
  if (idx < 5120) {
    int h = idx >> 6, e = idx & 63;
    float wa = W1[e * 80 + h], wb = W1[(64 + e) * 80 + h];
    float wc = W1[(128 + e) * 80 + h], wd = W1[(192 + e) * 80 + h];
    g_wkf[idx] = (f16)(wb - wc);
    g_wqf[idx] = (f16)wd;
    g_wsumT[idx] = (f16)(wa + wc);
  }
  if (idx < 4608) {
    int j = idx / 96, h = idx - j * 96;
    g_w2t[idx] = (h < 80 && j < 40) ? (f16)W2[h * 40 + j] : (f16)0.0f;
  }
}

// counting sort of b by keys_length DESCENDING -> perm (one block, 256 thr)
__global__ __launch_bounds__(256) void din_sort(const int* __restrict__ keys_length,
                                                int* __restrict__ perm) {
  __shared__ int hist[201];
  __shared__ int base[201];
  int t = threadIdx.x;
  for (int i = t; i < 201; i += 256) hist[i] = 0;
  __syncthreads();
  for (int b = t; b < Bn; b += 256) atomicAdd(&hist[keys_length[b]], 1);
  __syncthreads();
  if (t == 0) {
    int acc = 0;
    for (int l = 200; l >= 1; --l) { base[l] = acc; acc += hist[l]; }
    base[0] = acc;
  }
  __syncthreads();
  for (int i = t; i < 201; i += 256) hist[i] = 0;
  __syncthreads();
  for (int b = t; b < Bn; b += 256) {
    int l = keys_length[b];
    int pos = base[l] + atomicAdd(&hist[l], 1);
    perm[pos] = b;
  }
}

__global__ __launch_bounds__(64, 3) void din_main(
    const float* __restrict__ query,
    const float* __restrict__ keys,
    const int*   __restrict__ keys_length,
    const float* __restrict__ b1,
    const float* __restrict__ b2,
    const float* __restrict__ W3,
    const float* __restrict__ b3,
    const int*   __restrict__ perm,   // null => static mode (b = blockIdx.x)
    int*         __restrict__ ctr,
    float* __restrict__ out)
{
  __shared__ __align__(16) f16 hs[HSLAB];   // 2,784 B (one wave per block)
  __shared__ float sSw[16];

  const int lane = threadIdx.x;
  const int l15 = lane & 15;
  const int l4  = lane >> 4;
  const bool dyn = (perm != nullptr);

  // ---- b-independent setup (once per wave) ----
  const f16x8 zf = (f16x8)(f16)0.0f;
  for (int i = lane * 8; i < HSLAB; i += 512) *(f16x8*)&hs[i] = zf;

  f16x8 bw[3][3];
  #pragma unroll
  for (int n = 0; n < 3; ++n) {
    int c = n * 16 + l15;
    #pragma unroll
    for (int ks = 0; ks < 3; ++ks)
      bw[n][ks] = *(const f16x8*)&g_w2t[c * 96 + ks * 32 + l4 * 8];
  }
  float b2v[3], w3v[3];
  #pragma unroll
  for (int n = 0; n < 3; ++n) {
    int c = n * 16 + l15;
    b2v[n] = (c < 40) ? b2[c] : 0.0f;
    w3v[n] = (c < 40) ? W3[c] : 0.0f;
  }
  const float b3v = b3[0];

  // ---- persistent pop loop ----
  int idx = -1;
  for (;;) {
    if (dyn) {
      if (lane == 0) idx = atomicAdd(ctr, 1);
      idx = __shfl(idx, 0, 64);
      if (idx >= Bn) break;
    } else {
      if (idx >= 0) break;
      idx = blockIdx.x;
    }
    const int b = dyn ? perm[idx] : idx;

    const float* qp = query + (size_t)b * En;
    const float* kb = keys + (size_t)b * Tn * En;
    const int len = keys_length[b];
    const int mteb = (len + 15) >> 4;

    // ---- q fragments ----
    f16x8 qf0, qf1;
    {
      float4 qa = *(const float4*)(qp + l4 * 8);
      float4 qb = *(const float4*)(qp + l4 * 8 + 4);
      float4 qc = *(const float4*)(qp + 32 + l4 * 8);
      float4 qd = *(const float4*)(qp + 32 + l4 * 8 + 4);
      qf0 = pack8(qa, qb);
      qf1 = pack8(qc, qd);
    }

    // ---- qh[c] = b1[c] + q @ wsum[:,c] ----
    float qhv[5];
    #pragma unroll
    for (int n = 0; n < 5; ++n) {
      int c = n * 16 + l15;
      f16x8 ws0 = *(const f16x8*)&g_wsumT[c * 64 + l4 * 8];
      f16x8 ws1 = *(const f16x8*)&g_wsumT[c * 64 + 32 + l4 * 8];
      float p = 0.f;
      #pragma unroll
      for (int j = 0; j < 8; ++j)
        p += (float)qf0[j] * (float)ws0[j] + (float)qf1[j] * (float)ws1[j];
      p += __shfl_xor(p, 16, 64);
      p += __shfl_xor(p, 32, 64);
      qhv[n] = p + b1[c];
    }

    // ---- L1 B-fragments: Wb = wk + q*wqk ----
    f16x8 bf0[5], bf1[5];
    #pragma unroll
    for (int n = 0; n < 5; ++n) {
      int c = n * 16 + l15;
      bf0[n] = *(const f16x8*)&g_wkf[c * 64 + l4 * 8]
             + qf0 * *(const f16x8*)&g_wqf[c * 64 + l4 * 8];
      bf1[n] = *(const f16x8*)&g_wkf[c * 64 + 32 + l4 * 8]
             + qf1 * *(const f16x8*)&g_wqf[c * 64 + 32 + l4 * 8];
    }

    float poolA[8] = {0,0,0,0,0,0,0,0};
    float poolB[8] = {0,0,0,0,0,0,0,0};

    // ---- prefetch first tile ----
    float4 p0, p1, p2, p3;
    {
      const float* kr = kb + l15 * 64;
      p0 = *(const float4*)(kr + l4 * 8);
      p1 = *(const float4*)(kr + l4 * 8 + 4);
      p2 = *(const float4*)(kr + 32 + l4 * 8);
      p3 = *(const float4*)(kr + 32 + l4 * 8 + 4);
    }

    for (int mt = 0; mt < mteb; ++mt) {
      f16x8 ka = pack8(p0, p1);
      f16x8 kc = pack8(p2, p3);
      if (mt + 1 < mteb) {
        int r = (mt + 1) * 16 + l15; const float* kr = kb + (r < Tn ? r : Tn - 1) * 64;
        p0 = *(const float4*)(kr + l4 * 8);
        p1 = *(const float4*)(kr + l4 * 8 + 4);
        p2 = *(const float4*)(kr + 32 + l4 * 8);
        p3 = *(const float4*)(kr + 32 + l4 * 8 + 4);
      }

      // L1 + sigmoid -> H slab
      #pragma unroll
      for (int n = 0; n < 5; ++n) {
        f32x4 acc = {0.f, 0.f, 0.f, 0.f};
        acc = __builtin_amdgcn_mfma_f32_16x16x32_f16(ka, bf0[n], acc, 0, 0, 0);
        acc = __builtin_amdgcn_mfma_f32_16x16x32_f16(kc, bf1[n], acc, 0, 0, 0);
        int c = n * 16 + l15;
        #pragma unroll
        for (int i = 0; i < 4; ++i)
          hs[(l4 * 4 + i) * HS_W + c] = (f16)fsig(acc[i] + qhv[n]);
      }
      // H^T A-frags
      f16x8 aH0 = *(const f16x8*)&hs[l15 * HS_W + l4 * 8];
      f16x8 aH1 = *(const f16x8*)&hs[l15 * HS_W + 32 + l4 * 8];
      f16x8 aH2 = *(const f16x8*)&hs[l15 * HS_W + 64 + l4 * 8];

      // L2 (hoisted register B-frags) + sigmoid + W3 dot
      float sc[4] = {0.f, 0.f, 0.f, 0.f};
      #pragma unroll
      for (int n = 0; n < 3; ++n) {
        f32x4 acc = {0.f, 0.f, 0.f, 0.f};
        acc = __builtin_amdgcn_mfma_f32_16x16x32_f16(aH0, bw[n][0], acc, 0, 0, 0);
        acc = __builtin_amdgcn_mfma_f32_16x16x32_f16(aH1, bw[n][1], acc, 0, 0, 0);
        acc = __builtin_amdgcn_mfma_f32_16x16x32_f16(aH2, bw[n][2], acc, 0, 0, 0);
        #pragma unroll
        for (int i = 0; i < 4; ++i)
          sc[i] += fsig(acc[i] + b2v[n]) * w3v[n];
      }
      // reduce score over the 16 cols (l15) via DPP row_ror
      #pragma unroll
      for (int i = 0; i < 4; ++i) sc[i] = row16_sum(sc[i]);
      if (l15 == 0) {
        #pragma unroll
        for (int i = 0; i < 4; ++i) {
          int rr = mt * 16 + l4 * 4 + i;
          sSw[l4 * 4 + i] = (rr < len) ? sc[i] + b3v : 0.0f;
        }
      }
      float sv = sSw[l15];
      #pragma unroll
      for (int j = 0; j < 8; ++j) {
        poolA[j] += sv * (float)ka[j];
        poolB[j] += sv * (float)kc[j];
      }
    }

    // ---- pooling reduce + plain store (wave owns b) ----
    #pragma unroll
    for (int j = 0; j < 8; ++j) {
      poolA[j] = row16_sum(poolA[j]);
      poolB[j] = row16_sum(poolB[j]);
    }
    if (l15 == 0) {
      float* ob = out + (size_t)b * En;
      #pragma unroll
      for (int j = 0; j < 8; ++j) {
        ob[l4 * 8 + j] = poolA[j];
        ob[32 + l4 * 8 + j] = poolB[j];
      }
    }
  }
}

extern "C" void kernel_launch(void* const* d_in, const int* in_sizes, int n_in,
                              void* d_out, int out_size, void* d_ws, size_t ws_size,
                              hipStream_t stream) {
  const float* query       = (const float*)d_in[0];
  const float* keys        = (const float*)d_in[1];
  const int*   keys_length = (const int*)d_in[2];
  const float* W1 = (const float*)d_in[3];
  const float* b1 = (const float*)d_in[4];
  const float* W2 = (const float*)d_in[5];
  const float* b2 = (const float*)d_in[6];
  const float* W3 = (const float*)d_in[7];
  const float* b3 = (const float*)d_in[8];
  float* out = (float*)d_out;

  hipLaunchKernelGGL(din_prep, dim3(20), dim3(256), 0, stream, W1, W2);

  if (ws_size >= (64 + Bn) * sizeof(int)) {
    int* ctr  = (int*)d_ws;
    int* perm = (int*)d_ws + 64;
    hipMemsetAsync(ctr, 0, sizeof(int), stream);
    hipLaunchKernelGGL(din_sort, dim3(1), dim3(256), 0, stream, keys_length, perm);
    hipLaunchKernelGGL(din_main, dim3(1792), dim3(64), 0, stream,
                       query, keys, keys_length, b1, b2, W3, b3, perm, ctr, out);
  } else {
    hipLaunchKernelGGL(din_main, dim3(Bn), dim3(64), 0, stream,
                       query, keys, keys_length, b1, b2, W3, b3,
                       (const int*)nullptr, (int*)nullptr, out);
  }
}

// Round 21
// 49.190 us; speedup vs baseline: 1.7166x; 1.7166x over previous
//
#include <hip/hip_runtime.h>

// DIN attention pooling — round 21: len-skip + STATIC sorted-striped balance.
//   Wb[e][h] = (W1b-W1c)[e][h] + q_e*W1d[e][h];  qh[h] = b1[h] + q @ (W1a+W1c)
//   H = sig(K@Wb + qh); G = sig(H@W2 + b2); s = G@W3 + b3 (masked); out = s^T K
// R19: len-skip + natural order => per-CU length lottery, occupancy 12.6%,
// 61.9us. R20: dynamic LPT queue => atomics/sort/scatter overhead, 84us.
// R21: sort lengths DESCENDING once (1-block counting sort), then STATIC
// b = perm[blockIdx.x]. Round-robin dispatch stripes sorted ranks across
// CUs => every CU gets the same length spectrum => equal totals, no atomics.
// Body identical to R18 with mteb = ceil(len/16). Fallback: R18 (no skip).
// REGISTER LAW (R6/R8/R11 vs R7/R9/R12): keep the 170-reg class (bound ,3).

constexpr int Bn = 2048, Tn = 200, En = 64;
constexpr int HS_W  = 84;                // H slab stride (f16), conflict-free
constexpr int HSLAB = 16 * HS_W + 48;    // 1392: covers row-15 aH2 read to 1388

typedef _Float16 f16;
typedef _Float16 f16x2 __attribute__((ext_vector_type(2)));
typedef _Float16 f16x8 __attribute__((ext_vector_type(8)));
typedef float f32x4 __attribute__((ext_vector_type(4)));

__device__ __align__(16) f16 g_wkf[80 * 64];    // [h][e]  W1b - W1c
__device__ __align__(16) f16 g_wqf[80 * 64];    // [h][e]  W1d
__device__ __align__(16) f16 g_wsumT[80 * 64];  // [h][e]  W1a + W1c
__device__ __align__(16) f16 g_w2t[48 * 96];    // [j][h]  W2^T, zeros j>=40 or h>=80

__device__ __forceinline__ float fsig(float x) {
  return __fdividef(1.0f, 1.0f + __expf(-x));
}

template <int CTRL>
__device__ __forceinline__ float dpp_add(float x) {
  int y = __builtin_amdgcn_update_dpp(0, __builtin_bit_cast(int, x),
                                      CTRL, 0xf, 0xf, true);
  return x + __builtin_bit_cast(float, y);
}
__device__ __forceinline__ float row16_sum(float x) {
  x = dpp_add<0x121>(x);
  x = dpp_add<0x122>(x);
  x = dpp_add<0x124>(x);
  x = dpp_add<0x128>(x);
  return x;
}

__device__ __forceinline__ f16x8 pack8(float4 a, float4 b) {
  union { f16x2 p[4]; f16x8 v; } u;
  u.p[0] = __builtin_bit_cast(f16x2, __builtin_amdgcn_cvt_pkrtz(a.x, a.y));
  u.p[1] = __builtin_bit_cast(f16x2, __builtin_amdgcn_cvt_pkrtz(a.z, a.w));
  u.p[2] = __builtin_bit_cast(f16x2, __builtin_amdgcn_cvt_pkrtz(b.x, b.y));
  u.p[3] = __builtin_bit_cast(f16x2, __builtin_amdgcn_cvt_pkrtz(b.z, b.w));
  return u.v;
}

__global__ __launch_bounds__(256) void din_prep(const float* __restrict__ W1,
                                                const float* __restrict__ W2) {
  int idx = blockIdx.x * 256 + threadIdx.x;   // grid 20 -> 5120
  if (idx < 5120) {
    int h = idx >> 6, e = idx & 63;
    float wa = W1[e * 80 + h], wb = W1[(64 + e) * 80 + h];
    float wc = W1[(128 + e) * 80 + h], wd = W1[(192 + e) * 80 + h];
    g_wkf[idx] = (f16)(wb - wc);
    g_wqf[idx] = (f16)wd;
    g_wsumT[idx] = (f16)(wa + wc);
  }
  if (idx < 4608) {
    int j = idx / 96, h = idx - j * 96;
    g_w2t[idx] = (h < 80 && j < 40) ? (f16)W2[h * 40 + j] : (f16)0.0f;
  }
}

// counting sort of b by keys_length DESCENDING -> perm (one block, 256 thr)
__global__ __launch_bounds__(256) void din_sort(const int* __restrict__ keys_length,
                                                int* __restrict__ perm) {
  __shared__ int hist[201];
  __shared__ int base[201];
  int t = threadIdx.x;
  for (int i = t; i < 201; i += 256) hist[i] = 0;
  __syncthreads();
  for (int b = t; b < Bn; b += 256) atomicAdd(&hist[keys_length[b]], 1);
  __syncthreads();
  if (t == 0) {
    int acc = 0;
    for (int l = 200; l >= 1; --l) { base[l] = acc; acc += hist[l]; }
    base[0] = acc;
  }
  __syncthreads();
  for (int i = t; i < 201; i += 256) hist[i] = 0;
  __syncthreads();
  for (int b = t; b < Bn; b += 256) {
    int l = keys_length[b];
    int pos = base[l] + atomicAdd(&hist[l], 1);
    perm[pos] = b;
  }
}

template <bool SKIP>
__global__ __launch_bounds__(64, 3) void din_main(
    const float* __restrict__ query,
    const float* __restrict__ keys,
    const int*   __restrict__ keys_length,
    const float* __restrict__ b1,
    const float* __restrict__ b2,
    const float* __restrict__ W3,
    const float* __restrict__ b3,
    const int*   __restrict__ perm,
    float* __restrict__ out)
{
  __shared__ __align__(16) f16 hs[HSLAB];   // 2,784 B (one wave per block)
  __shared__ float sSw[16];

  const int lane = threadIdx.x;
  const int l15 = lane & 15;
  const int l4  = lane >> 4;

  const int b = SKIP ? perm[blockIdx.x] : blockIdx.x;

  const float* qp = query + (size_t)b * En;
  const float* kb = keys + (size_t)b * Tn * En;
  const int len = keys_length[b];
  const int mteb = SKIP ? ((len + 15) >> 4) : 13;
  const float b3v = b3[0];

  // ---- zero slab (cols 80..95 + pad must read 0.0 in L2 MFMAs) ----
  const f16x8 zf = (f16x8)(f16)0.0f;
  for (int i = lane * 8; i < HSLAB; i += 512) *(f16x8*)&hs[i] = zf;

  // ---- HOISTED loop-invariant W2 B-frags: bw[n][ks], 9 x f16x8 = 36 VGPRs --
  f16x8 bw[3][3];
  #pragma unroll
  for (int n = 0; n < 3; ++n) {
    int c = n * 16 + l15;
    #pragma unroll
    for (int ks = 0; ks < 3; ++ks)
      bw[n][ks] = *(const f16x8*)&g_w2t[c * 96 + ks * 32 + l4 * 8];
  }

  // ---- q fragments (f16) ----
  f16x8 qf0, qf1;
  {
    float4 qa = *(const float4*)(qp + l4 * 8);
    float4 qb = *(const float4*)(qp + l4 * 8 + 4);
    float4 qc = *(const float4*)(qp + 32 + l4 * 8);
    float4 qd = *(const float4*)(qp + 32 + l4 * 8 + 4);
    qf0 = pack8(qa, qb);
    qf1 = pack8(qc, qd);
  }

  // ---- qh[c] = b1[c] + q @ wsum[:,c] via VALU dot + shfl over l4 ----
  float qhv[5];
  #pragma unroll
  for (int n = 0; n < 5; ++n) {
    int c = n * 16 + l15;
    f16x8 ws0 = *(const f16x8*)&g_wsumT[c * 64 + l4 * 8];
    f16x8 ws1 = *(const f16x8*)&g_wsumT[c * 64 + 32 + l4 * 8];
    float p = 0.f;
    #pragma unroll
    for (int j = 0; j < 8; ++j)
      p += (float)qf0[j] * (float)ws0[j] + (float)qf1[j] * (float)ws1[j];
    p += __shfl_xor(p, 16, 64);
    p += __shfl_xor(p, 32, 64);
    qhv[n] = p + b1[c];
  }

  // ---- L1 B-fragments: Wb = wk + q*wqk (elementwise f16) ----
  f16x8 bf0[5], bf1[5];
  #pragma unroll
  for (int n = 0; n < 5; ++n) {
    int c = n * 16 + l15;
    bf0[n] = *(const f16x8*)&g_wkf[c * 64 + l4 * 8]
           + qf0 * *(const f16x8*)&g_wqf[c * 64 + l4 * 8];
    bf1[n] = *(const f16x8*)&g_wkf[c * 64 + 32 + l4 * 8]
           + qf1 * *(const f16x8*)&g_wqf[c * 64 + 32 + l4 * 8];
  }

  // ---- per-col constants for L2/L3 ----
  float b2v[3], w3v[3];
  #pragma unroll
  for (int n = 0; n < 3; ++n) {
    int c = n * 16 + l15;
    b2v[n] = (c < 40) ? b2[c] : 0.0f;
    w3v[n] = (c < 40) ? W3[c] : 0.0f;
  }

  float poolA[8] = {0,0,0,0,0,0,0,0};
  float poolB[8] = {0,0,0,0,0,0,0,0};

  // ---- prefetch first tile's keys rows ----
  float4 p0, p1, p2, p3;
  {
    const float* kr = kb + l15 * 64;
    p0 = *(const float4*)(kr + l4 * 8);
    p1 = *(const float4*)(kr + l4 * 8 + 4);
    p2 = *(const float4*)(kr + 32 + l4 * 8);
    p3 = *(const float4*)(kr + 32 + l4 * 8 + 4);
  }

  for (int mt = 0; mt < mteb; ++mt) {
    f16x8 ka = pack8(p0, p1);
    f16x8 kc = pack8(p2, p3);
    // issue next tile's loads under this tile's compute
    if (mt + 1 < mteb) {
      int r = (mt + 1) * 16 + l15; const float* kr = kb + (r < Tn ? r : Tn - 1) * 64;
      p0 = *(const float4*)(kr + l4 * 8);
      p1 = *(const float4*)(kr + l4 * 8 + 4);
      p2 = *(const float4*)(kr + 32 + l4 * 8);
      p3 = *(const float4*)(kr + 32 + l4 * 8 + 4);
    }

    // L1 + sigmoid -> H slab, per n (acc liveness = 4)
    #pragma unroll
    for (int n = 0; n < 5; ++n) {
      f32x4 acc = {0.f, 0.f, 0.f, 0.f};
      acc = __builtin_amdgcn_mfma_f32_16x16x32_f16(ka, bf0[n], acc, 0, 0, 0);
      acc = __builtin_amdgcn_mfma_f32_16x16x32_f16(kc, bf1[n], acc, 0, 0, 0);
      int c = n * 16 + l15;
      #pragma unroll
      for (int i = 0; i < 4; ++i)
        hs[(l4 * 4 + i) * HS_W + c] = (f16)fsig(acc[i] + qhv[n]);
    }
    // H^T A-frags
    f16x8 aH0 = *(const f16x8*)&hs[l15 * HS_W + l4 * 8];
    f16x8 aH1 = *(const f16x8*)&hs[l15 * HS_W + 32 + l4 * 8];
    f16x8 aH2 = *(const f16x8*)&hs[l15 * HS_W + 64 + l4 * 8];

    // L2 (hoisted register B-frags) + sigmoid + W3 dot
    float sc[4] = {0.f, 0.f, 0.f, 0.f};
    #pragma unroll
    for (int n = 0; n < 3; ++n) {
      f32x4 acc = {0.f, 0.f, 0.f, 0.f};
      acc = __builtin_amdgcn_mfma_f32_16x16x32_f16(aH0, bw[n][0], acc, 0, 0, 0);
      acc = __builtin_amdgcn_mfma_f32_16x16x32_f16(aH1, bw[n][1], acc, 0, 0, 0);
      acc = __builtin_amdgcn_mfma_f32_16x16x32_f16(aH2, bw[n][2], acc, 0, 0, 0);
      #pragma unroll
      for (int i = 0; i < 4; ++i)
        sc[i] += fsig(acc[i] + b2v[n]) * w3v[n];
    }
    // reduce score over the 16 cols (l15) via DPP row_ror — no LDS pipe
    #pragma unroll
    for (int i = 0; i < 4; ++i) sc[i] = row16_sum(sc[i]);
    if (l15 == 0) {
      #pragma unroll
      for (int i = 0; i < 4; ++i) {
        int rr = mt * 16 + l4 * 4 + i;
        sSw[l4 * 4 + i] = (rr < len) ? sc[i] + b3v : 0.0f;
      }
    }
    // broadcast this lane's row score (same-wave LDS, in-order per wave)
    float sv = sSw[l15];
    #pragma unroll
    for (int j = 0; j < 8; ++j) {
      poolA[j] += sv * (float)ka[j];
      poolB[j] += sv * (float)kc[j];
    }
  }

  // ---- reduce pooling over the 16 rows (l15) via DPP row_ror ----
  #pragma unroll
  for (int j = 0; j < 8; ++j) {
    poolA[j] = row16_sum(poolA[j]);
    poolB[j] = row16_sum(poolB[j]);
  }
  // wave owns the full b: plain store (no atomics, no memset)
  if (l15 == 0) {
    float* ob = out + (size_t)b * En;
    #pragma unroll
    for (int j = 0; j < 8; ++j) {
      ob[l4 * 8 + j] = poolA[j];
      ob[32 + l4 * 8 + j] = poolB[j];
    }
  }
}

extern "C" void kernel_launch(void* const* d_in, const int* in_sizes, int n_in,
                              void* d_out, int out_size, void* d_ws, size_t ws_size,
                              hipStream_t stream) {
  const float* query       = (const float*)d_in[0];
  const float* keys        = (const float*)d_in[1];
  const int*   keys_length = (const int*)d_in[2];
  const float* W1 = (const float*)d_in[3];
  const float* b1 = (const float*)d_in[4];
  const float* W2 = (const float*)d_in[5];
  const float* b2 = (const float*)d_in[6];
  const float* W3 = (const float*)d_in[7];
  const float* b3 = (const float*)d_in[8];
  float* out = (float*)d_out;

  hipLaunchKernelGGL(din_prep, dim3(20), dim3(256), 0, stream, W1, W2);

  if (ws_size >= Bn * sizeof(int)) {
    int* perm = (int*)d_ws;
    hipLaunchKernelGGL(din_sort, dim3(1), dim3(256), 0, stream, keys_length, perm);
    hipLaunchKernelGGL((din_main<true>), dim3(Bn), dim3(64), 0, stream,
                       query, keys, keys_length, b1, b2, W3, b3, perm, out);
  } else {
    hipLaunchKernelGGL((din_main<false>), dim3(Bn), dim3(64), 0, stream,
                       query, keys, keys_length, b1, b2, W3, b3,
                       (const int*)nullptr, out);
  }
}